// Round 10
// baseline (53.840 us; speedup 1.0000x reference)
//
#include <hip/hip_runtime.h>

#define N_NODES 6144
#define ATTD 128
#define HIDD 96
#define EPT 100000
#define NTYPE 3
#define NEDGE (NTYPE * EPT)
#define BCAP 128                      // per-row bucket capacity (max deg ~85)
#define CPAD 16                       // row-counter padding: 16 ints = 64B line
#define PSTRIDE 16                    // partial-cell padding: 64B line
#define NCELL 64                      // partial accumulator cells
#define NEG 0.2f
#define BUCKET_BLOCKS ((NEDGE + 255) / 256)   // 1172
#define MLP_BLOCKS (N_NODES / 4)              // 1536 (4 rows / block, 2 passes)
#define ZBYTES (2 * NCELL * PSTRIDE * 4 + N_NODES * CPAD * 4)   // 401408
#define ZVEC (ZBYTES / 16)                                      // 25088 float4
#define ZBLK (ZVEC / 256)                                       // 98

// ---- k0: zero part0|part1|rcnt (contiguous at ws start). NOT hipMemsetAsync:
// the driver fill kernel costs ~39us regardless of size (measured r9). ----
__global__ void k_zero(float4* __restrict__ p) {
    int i = blockIdx.x * blockDim.x + threadIdx.x;
    p[i] = make_float4(0.f, 0.f, 0.f, 0.f);
}

// ---- k1 (fused): bucket edges by row (ushort entries) | MLP + part0 ----
__global__ void k_build(const int* __restrict__ edges, int* __restrict__ rcnt,
                        unsigned short* __restrict__ bucket,
                        const float* __restrict__ X, const float* __restrict__ W1,
                        const float* __restrict__ b1, const float* __restrict__ W2,
                        const float* __restrict__ b2, float* __restrict__ s,
                        float* __restrict__ part0) {
    int bid = blockIdx.x;
    if (bid < BUCKET_BLOCKS) {
        int k = bid * 256 + threadIdx.x;
        if (k < NEDGE) {
            int t = k / EPT;
            int e = k - t * EPT;
            int src = edges[t * (2 * EPT) + e];
            int tgt = edges[t * (2 * EPT) + EPT + e];
            int pos = atomicAdd(&rcnt[src * CPAD], 1);
            if (pos < BCAP)
                bucket[src * BCAP + pos] = (unsigned short)((t << 13) | tgt);
        }
        return;
    }
    // ---- MLP: s = leaky(X@W1+b1)@W2 + b2, 4 rows per block (2 passes x 2) ----
    int mbid = bid - BUCKET_BLOCKS;
    const int half = threadIdx.x >> 7;    // 0 or 1
    const int t128 = threadIdx.x & 127;
    __shared__ float xs[2][ATTD];
    __shared__ float red[2][2];
    __shared__ float sred[2];
    float blocksum = 0.f;                 // meaningful on tid 0 only
    for (int pass = 0; pass < 2; ++pass) {
        int row = (mbid << 2) + (pass << 1) + half;
        __syncthreads();
        xs[half][t128] = X[row * ATTD + t128];
        __syncthreads();
        float val = 0.f;
        if (t128 < HIDD) {
            float acc = b1[t128];
#pragma unroll 8
            for (int k = 0; k < ATTD; ++k) acc += xs[half][k] * W1[k * HIDD + t128];
            float h = acc > 0.f ? acc : NEG * acc;
            val = h * W2[t128];
        }
#pragma unroll
        for (int off = 32; off; off >>= 1) val += __shfl_down(val, off, 64);
        if ((threadIdx.x & 63) == 0) red[half][t128 >> 6] = val;
        __syncthreads();
        if (t128 == 0) {
            float r = red[half][0] + red[half][1] + b2[0];
            s[row] = r;
            sred[half] = r;
        }
        __syncthreads();
        if (threadIdx.x == 0) blocksum += sred[0] + sred[1];
    }
    if (threadIdx.x == 0)
        atomicAdd(&part0[(mbid & (NCELL - 1)) * PSTRIDE], blocksum);
}

// ---- k2: per-row LDS dedup + layer-0 gather; packed merged list + part1 ----
// merged entry: v | c0<<13 | c1<<19 | c2<<25 (counts <=63 — duplicates are rare)
__global__ void k_gather1(const int* __restrict__ rcnt,
                          const unsigned short* __restrict__ bucket,
                          const float* __restrict__ s,
                          const float* __restrict__ edge_emb,
                          const float* __restrict__ attn_w,
                          const float* __restrict__ part0, float* __restrict__ s2,
                          int* __restrict__ mlist, int* __restrict__ cnt2,
                          float* __restrict__ part1) {
    int tid = threadIdx.x, lane = tid & 63, wv = tid >> 6, bid = blockIdx.x;
    __shared__ int hk[4 * 256];
    __shared__ int hc[4 * 256];
    __shared__ float pl[32];
    __shared__ float stot_s;
    __shared__ float wsum[4];
    if (tid < 4) {
        const float* w = attn_w + tid * 22;   // (2,2,22,1) flat
        float* p = pl + tid * 8;
        p[0] = w[0];
        p[1] = w[21];
        for (int ty = 0; ty < NTYPE; ++ty) {
            float acc = 0.f;
            for (int j = 0; j < 20; ++j) acc += edge_emb[ty * 20 + j] * w[1 + j];
            p[2 + ty] = acc;
        }
    }
    int* K = hk + wv * 256;
    int* C = hc + wv * 256;
#pragma unroll
    for (int j = lane; j < 256; j += 64) { K[j] = -1; C[j] = 0; }
    if (wv == 0) {
        float v = part0[lane * PSTRIDE];
#pragma unroll
        for (int off = 32; off; off >>= 1) v += __shfl_down(v, off, 64);
        if (lane == 0) stot_s = v;
    }
    __syncthreads();
    const int u = bid * 4 + wv;
    {
        int d = rcnt[u * CPAD];
        if (d > BCAP) d = BCAP;
        for (int i = lane; i < d; i += 64) {
            int raw = bucket[u * BCAP + i];
            int v = raw & 8191;
            int t = raw >> 13;
            unsigned slot = ((unsigned)v * 2654435761u) >> 24;  // 8-bit slot
            while (true) {
                int prev = atomicCAS(&K[slot], -1, v);
                if (prev == -1 || prev == v) break;
                slot = (slot + 1) & 255;
            }
            atomicAdd(&C[slot], 1 << (10 * t));
        }
    }
    __syncthreads();
    float su = s[u];
    float w00 = pl[0], w01 = pl[1], e00 = pl[2], e01 = pl[3], e02 = pl[4];
    float w10 = pl[8], w11 = pl[9], e10 = pl[10], e11 = pl[11], e12 = pl[12];
    float num0 = 0.f, den0 = 0.f, num1 = 0.f, den1 = 0.f;
    int base = 0;
#pragma unroll
    for (int it = 0; it < 4; ++it) {
        int j = it * 64 + lane;
        int key = K[j];
        bool live = key >= 0;
        unsigned long long m = __ballot(live);
        if (live) {
            int cw = C[j];
            int ic0 = cw & 1023, ic1 = (cw >> 10) & 1023, ic2 = (cw >> 20) & 1023;
            int idx = base + __popcll(m & ((1ull << lane) - 1ull));
            mlist[u * BCAP + idx] = key | (ic0 << 13) | (ic1 << 19) | (ic2 << 25);
            float c0 = (float)ic0, c1 = (float)ic1, c2 = (float)ic2;
            float Cc = c0 + c1 + c2;
            float sv = s[key];
            float A0 = Cc * (w00 * su + w01 * sv) + c0 * e00 + c1 * e01 + c2 * e02;
            float la0 = A0 > 0.f ? A0 : NEG * A0;
            float g0 = expf(la0) - 1.f;
            num0 += g0 * sv; den0 += g0;
            float A1 = Cc * (w10 * su + w11 * sv) + c0 * e10 + c1 * e11 + c2 * e12;
            float la1 = A1 > 0.f ? A1 : NEG * A1;
            float g1 = expf(la1) - 1.f;
            num1 += g1 * sv; den1 += g1;
        }
        base += __popcll(m);
    }
#pragma unroll
    for (int off = 32; off; off >>= 1) {
        num0 += __shfl_down(num0, off, 64);
        den0 += __shfl_down(den0, off, 64);
        num1 += __shfl_down(num1, off, 64);
        den1 += __shfl_down(den1, off, 64);
    }
    if (lane == 0) {
        cnt2[u] = base;
        float S = stot_s;
        float r0 = (S + num0) / ((float)N_NODES + den0);
        float r1 = (S + num1) / ((float)N_NODES + den1);
        float val = 0.5f * (r0 + r1);
        s2[u] = val;
        wsum[wv] = val;
    }
    __syncthreads();
    if (tid == 0)
        atomicAdd(&part1[(bid & (NCELL - 1)) * PSTRIDE],
                  wsum[0] + wsum[1] + wsum[2] + wsum[3]);
}

// ---- k3: layer-1 gather over packed merged lists (1 int load / edge) ----
__global__ void k_gather2(const int* __restrict__ cnt2, const int* __restrict__ mlist,
                          const float* __restrict__ s,
                          const float* __restrict__ edge_emb,
                          const float* __restrict__ attn_w,
                          const float* __restrict__ part1, float* __restrict__ dst) {
    int tid = threadIdx.x, lane = tid & 63, wv = tid >> 6, bid = blockIdx.x;
    __shared__ float pl[32];
    __shared__ float stot_s;
    if (tid < 4) {
        const float* w = attn_w + tid * 22;
        float* p = pl + tid * 8;
        p[0] = w[0];
        p[1] = w[21];
        for (int ty = 0; ty < NTYPE; ++ty) {
            float acc = 0.f;
            for (int j = 0; j < 20; ++j) acc += edge_emb[ty * 20 + j] * w[1 + j];
            p[2 + ty] = acc;
        }
    }
    if (wv == 0) {
        float v = part1[lane * PSTRIDE];
#pragma unroll
        for (int off = 32; off; off >>= 1) v += __shfl_down(v, off, 64);
        if (lane == 0) stot_s = v;
    }
    __syncthreads();
    const int u = bid * 4 + wv;
    float su = s[u];
    float w00 = pl[16], w01 = pl[17], e00 = pl[18], e01 = pl[19], e02 = pl[20];
    float w10 = pl[24], w11 = pl[25], e10 = pl[26], e11 = pl[27], e12 = pl[28];
    float num0 = 0.f, den0 = 0.f, num1 = 0.f, den1 = 0.f;
    int d = cnt2[u];
    for (int i = lane; i < d; i += 64) {
        int p = mlist[u * BCAP + i];
        int v = p & 8191;
        float c0 = (float)((p >> 13) & 63);
        float c1 = (float)((p >> 19) & 63);
        float c2 = (float)((p >> 25) & 63);
        float Cc = c0 + c1 + c2;
        float sv = s[v];
        float A0 = Cc * (w00 * su + w01 * sv) + c0 * e00 + c1 * e01 + c2 * e02;
        float la0 = A0 > 0.f ? A0 : NEG * A0;
        float g0 = expf(la0) - 1.f;
        num0 += g0 * sv; den0 += g0;
        float A1 = Cc * (w10 * su + w11 * sv) + c0 * e10 + c1 * e11 + c2 * e12;
        float la1 = A1 > 0.f ? A1 : NEG * A1;
        float g1 = expf(la1) - 1.f;
        num1 += g1 * sv; den1 += g1;
    }
#pragma unroll
    for (int off = 32; off; off >>= 1) {
        num0 += __shfl_down(num0, off, 64);
        den0 += __shfl_down(den0, off, 64);
        num1 += __shfl_down(num1, off, 64);
        den1 += __shfl_down(den1, off, 64);
    }
    if (lane == 0) {
        float S = stot_s;
        float r0 = (S + num0) / ((float)N_NODES + den0);
        float r1 = (S + num1) / ((float)N_NODES + den1);
        dst[u] = 0.5f * (r0 + r1);
    }
}

extern "C" void kernel_launch(void* const* d_in, const int* in_sizes, int n_in,
                              void* d_out, int out_size, void* d_ws, size_t ws_size,
                              hipStream_t stream) {
    const float* X        = (const float*)d_in[0];
    const int*   edges    = (const int*)d_in[1];
    const float* W1       = (const float*)d_in[2];
    const float* b1       = (const float*)d_in[3];
    const float* W2       = (const float*)d_in[4];
    const float* b2       = (const float*)d_in[5];
    const float* edge_emb = (const float*)d_in[6];
    const float* attn_w   = (const float*)d_in[7];
    float* out = (float*)d_out;

    char* w = (char*)d_ws;
    float* part0  = (float*)w; w += NCELL * PSTRIDE * sizeof(float);
    float* part1  = (float*)w; w += NCELL * PSTRIDE * sizeof(float);
    int*   rcnt   = (int*)w;   w += N_NODES * CPAD * sizeof(int);
    float* s      = (float*)w; w += N_NODES * sizeof(float);
    float* s2     = (float*)w; w += N_NODES * sizeof(float);
    int*   cnt2   = (int*)w;   w += N_NODES * sizeof(int);
    int*   mlist  = (int*)w;   w += N_NODES * BCAP * sizeof(int);
    unsigned short* bucket = (unsigned short*)w;

    k_zero<<<ZBLK, 256, 0, stream>>>((float4*)d_ws);
    k_build<<<BUCKET_BLOCKS + MLP_BLOCKS, 256, 0, stream>>>(edges, rcnt, bucket,
                                                            X, W1, b1, W2, b2, s, part0);
    k_gather1<<<N_NODES / 4, 256, 0, stream>>>(rcnt, bucket, s, edge_emb, attn_w,
                                               part0, s2, mlist, cnt2, part1);
    k_gather2<<<N_NODES / 4, 256, 0, stream>>>(cnt2, mlist, s2, edge_emb, attn_w,
                                               part1, out);
}

// Round 11
// 51.187 us; speedup vs baseline: 1.0518x; 1.0518x over previous
//
#include <hip/hip_runtime.h>

#define N_NODES 6144
#define ATTD 128
#define HIDD 96
#define EPT 100000
#define NTYPE 3
#define NEDGE (NTYPE * EPT)
#define BCAP 128                      // per-row bucket capacity (max deg ~85)
#define CPAD 16                       // row-counter padding: 16 ints = 64B line
#define PSTRIDE 16                    // partial-cell padding: 64B line
#define NCELL 64                      // partial accumulator cells
#define NEG 0.2f
#define BUCKET_BLOCKS ((NEDGE + 255) / 256)   // 1172
#define MLP_BLOCKS (N_NODES / 2)              // 3072 (2 rows / 256-thr block)

// ---- k0: zero padded row counters + partial cells, compute per-(l,h) params ----
__global__ void k_init(const float* __restrict__ attn_w,
                       const float* __restrict__ edge_emb,
                       float* __restrict__ params, int* __restrict__ rcnt,
                       float* __restrict__ part0, float* __restrict__ part1) {
    int i = blockIdx.x * blockDim.x + threadIdx.x;
    if (i < N_NODES * CPAD) rcnt[i] = 0;
    if (i < NCELL * PSTRIDE) { part0[i] = 0.f; part1[i] = 0.f; }
    if (i < 4) {
        // attn_w flat: (2,2,22,1) -> (l*2+h)*22 + j
        const float* w = attn_w + i * 22;
        float* p = params + i * 8;
        p[0] = w[0];    // w0 (src coeff)
        p[1] = w[21];   // w_last (tgt coeff)
        for (int ty = 0; ty < NTYPE; ++ty) {
            float acc = 0.f;
            for (int j = 0; j < 20; ++j) acc += edge_emb[ty * 20 + j] * w[1 + j];
            p[2 + ty] = acc;
        }
    }
}

// ---- k1 (fused): bucket edges by row  |  MLP scores + stot0 partials ----
__global__ void k_build(const int* __restrict__ edges, int* __restrict__ rcnt,
                        int* __restrict__ bucket,
                        const float* __restrict__ X, const float* __restrict__ W1,
                        const float* __restrict__ b1, const float* __restrict__ W2,
                        const float* __restrict__ b2, float* __restrict__ s,
                        float* __restrict__ part0) {
    int bid = blockIdx.x;
    if (bid < BUCKET_BLOCKS) {
        int k = bid * 256 + threadIdx.x;
        if (k < NEDGE) {
            int t = k / EPT;
            int e = k - t * EPT;
            int src = edges[t * (2 * EPT) + e];
            int tgt = edges[t * (2 * EPT) + EPT + e];
            int pos = atomicAdd(&rcnt[src * CPAD], 1);
            if (pos < BCAP) bucket[src * BCAP + pos] = (t << 13) | tgt;
        }
        return;
    }
    // ---- MLP: s = leaky(X@W1+b1)@W2 + b2, two rows per block ----
    int half = threadIdx.x >> 7;          // 0 or 1
    int tid  = threadIdx.x & 127;
    int mbid = bid - BUCKET_BLOCKS;
    int row  = mbid * 2 + half;
    __shared__ float xs[2][ATTD];
    __shared__ float red[2][2];
    __shared__ float sred[2];
    xs[half][tid] = X[row * ATTD + tid];
    __syncthreads();
    float val = 0.f;
    if (tid < HIDD) {
        float acc = b1[tid];
#pragma unroll 8
        for (int k = 0; k < ATTD; ++k) acc += xs[half][k] * W1[k * HIDD + tid];
        float h = acc > 0.f ? acc : NEG * acc;
        val = h * W2[tid];
    }
#pragma unroll
    for (int off = 32; off; off >>= 1) val += __shfl_down(val, off, 64);
    if ((threadIdx.x & 63) == 0) red[half][tid >> 6] = val;
    __syncthreads();
    if (tid == 0) {
        float r = red[half][0] + red[half][1] + b2[0];
        s[row] = r;
        sred[half] = r;
    }
    __syncthreads();
    if (threadIdx.x == 0)
        atomicAdd(&part0[(mbid & (NCELL - 1)) * PSTRIDE], sred[0] + sred[1]);
}

// ---- k2: per-row LDS dedup + layer-0 gather; packed merged list + part1 ----
// merged entry: v | c0<<13 | c1<<19 | c2<<25 (dup counts <=63 — duplicates rare)
__global__ void k_gather1(const int* __restrict__ rcnt, const int* __restrict__ bucket,
                          const float* __restrict__ s, const float* __restrict__ params,
                          const float* __restrict__ part0, float* __restrict__ s2,
                          int* __restrict__ mlist, int* __restrict__ cnt2,
                          float* __restrict__ part1) {
    int lane = threadIdx.x & 63;
    int wv   = threadIdx.x >> 6;
    int bid  = blockIdx.x;
    int u    = bid * 4 + wv;
    __shared__ int hk[4 * 256];
    __shared__ int hc[4 * 256];
    __shared__ float stot_s;
    __shared__ float wsum[4];
    int* K = hk + wv * 256;
    int* C = hc + wv * 256;
#pragma unroll
    for (int j = lane; j < 256; j += 64) { K[j] = -1; C[j] = 0; }
    if (wv == 0) {
        float v = part0[lane * PSTRIDE];
#pragma unroll
        for (int off = 32; off; off >>= 1) v += __shfl_down(v, off, 64);
        if (lane == 0) stot_s = v;
    }
    __syncthreads();
    int d = rcnt[u * CPAD];
    if (d > BCAP) d = BCAP;
    for (int i = lane; i < d; i += 64) {
        int raw = bucket[u * BCAP + i];
        int v = raw & 8191;
        int t = raw >> 13;
        unsigned slot = ((unsigned)v * 2654435761u) >> 24;  // 8-bit slot
        while (true) {
            int prev = atomicCAS(&K[slot], -1, v);
            if (prev == -1 || prev == v) break;
            slot = (slot + 1) & 255;
        }
        atomicAdd(&C[slot], 1 << (10 * t));
    }
    __syncthreads();
    const float* p0 = params + 0;
    const float* p1 = params + 8;
    float su = s[u];
    float w00 = p0[0], w01 = p0[1], e00 = p0[2], e01 = p0[3], e02 = p0[4];
    float w10 = p1[0], w11 = p1[1], e10 = p1[2], e11 = p1[3], e12 = p1[4];
    float num0 = 0.f, den0 = 0.f, num1 = 0.f, den1 = 0.f;
    int base = 0;
#pragma unroll
    for (int it = 0; it < 4; ++it) {
        int j = it * 64 + lane;
        int key = K[j];
        bool live = key >= 0;
        unsigned long long m = __ballot(live);
        if (live) {
            int cw = C[j];
            int ic0 = cw & 1023, ic1 = (cw >> 10) & 1023, ic2 = (cw >> 20) & 1023;
            int idx = base + __popcll(m & ((1ull << lane) - 1ull));
            mlist[u * BCAP + idx] = key | (ic0 << 13) | (ic1 << 19) | (ic2 << 25);
            float c0 = (float)ic0, c1 = (float)ic1, c2 = (float)ic2;
            float Cc = c0 + c1 + c2;
            float sv = s[key];
            float A0 = Cc * (w00 * su + w01 * sv) + c0 * e00 + c1 * e01 + c2 * e02;
            float la0 = A0 > 0.f ? A0 : NEG * A0;
            float g0 = expf(la0) - 1.f;
            num0 += g0 * sv; den0 += g0;
            float A1 = Cc * (w10 * su + w11 * sv) + c0 * e10 + c1 * e11 + c2 * e12;
            float la1 = A1 > 0.f ? A1 : NEG * A1;
            float g1 = expf(la1) - 1.f;
            num1 += g1 * sv; den1 += g1;
        }
        base += __popcll(m);
    }
#pragma unroll
    for (int off = 32; off; off >>= 1) {
        num0 += __shfl_down(num0, off, 64);
        den0 += __shfl_down(den0, off, 64);
        num1 += __shfl_down(num1, off, 64);
        den1 += __shfl_down(den1, off, 64);
    }
    if (lane == 0) {
        cnt2[u] = base;
        float S = stot_s;
        float r0 = (S + num0) / ((float)N_NODES + den0);
        float r1 = (S + num1) / ((float)N_NODES + den1);
        float val = 0.5f * (r0 + r1);
        s2[u] = val;
        wsum[wv] = val;
    }
    __syncthreads();
    if (threadIdx.x == 0)
        atomicAdd(&part1[(bid & (NCELL - 1)) * PSTRIDE],
                  wsum[0] + wsum[1] + wsum[2] + wsum[3]);
}

// ---- k3: layer-1 gather over packed merged lists (1 int load / edge) ----
__global__ void k_gather2(const int* __restrict__ cnt2, const int* __restrict__ mlist,
                          const float* __restrict__ s, const float* __restrict__ params,
                          const float* __restrict__ part1, float* __restrict__ dst) {
    int lane = threadIdx.x & 63;
    int wv   = threadIdx.x >> 6;
    int u    = blockIdx.x * 4 + wv;
    __shared__ float stot_s;
    if (wv == 0) {
        float v = part1[lane * PSTRIDE];
#pragma unroll
        for (int off = 32; off; off >>= 1) v += __shfl_down(v, off, 64);
        if (lane == 0) stot_s = v;
    }
    __syncthreads();
    float su = s[u];
    const float* p0 = params + 16;
    const float* p1 = params + 24;
    float w00 = p0[0], w01 = p0[1], e00 = p0[2], e01 = p0[3], e02 = p0[4];
    float w10 = p1[0], w11 = p1[1], e10 = p1[2], e11 = p1[3], e12 = p1[4];
    float num0 = 0.f, den0 = 0.f, num1 = 0.f, den1 = 0.f;
    int d = cnt2[u];
    for (int i = lane; i < d; i += 64) {
        int p = mlist[u * BCAP + i];
        int v = p & 8191;
        float c0 = (float)((p >> 13) & 63);
        float c1 = (float)((p >> 19) & 63);
        float c2 = (float)((p >> 25) & 63);
        float Cc = c0 + c1 + c2;
        float sv = s[v];
        float A0 = Cc * (w00 * su + w01 * sv) + c0 * e00 + c1 * e01 + c2 * e02;
        float la0 = A0 > 0.f ? A0 : NEG * A0;
        float g0 = expf(la0) - 1.f;
        num0 += g0 * sv; den0 += g0;
        float A1 = Cc * (w10 * su + w11 * sv) + c0 * e10 + c1 * e11 + c2 * e12;
        float la1 = A1 > 0.f ? A1 : NEG * A1;
        float g1 = expf(la1) - 1.f;
        num1 += g1 * sv; den1 += g1;
    }
#pragma unroll
    for (int off = 32; off; off >>= 1) {
        num0 += __shfl_down(num0, off, 64);
        den0 += __shfl_down(den0, off, 64);
        num1 += __shfl_down(num1, off, 64);
        den1 += __shfl_down(den1, off, 64);
    }
    if (lane == 0) {
        float S = stot_s;
        float r0 = (S + num0) / ((float)N_NODES + den0);
        float r1 = (S + num1) / ((float)N_NODES + den1);
        dst[u] = 0.5f * (r0 + r1);
    }
}

extern "C" void kernel_launch(void* const* d_in, const int* in_sizes, int n_in,
                              void* d_out, int out_size, void* d_ws, size_t ws_size,
                              hipStream_t stream) {
    const float* X        = (const float*)d_in[0];
    const int*   edges    = (const int*)d_in[1];
    const float* W1       = (const float*)d_in[2];
    const float* b1       = (const float*)d_in[3];
    const float* W2       = (const float*)d_in[4];
    const float* b2       = (const float*)d_in[5];
    const float* edge_emb = (const float*)d_in[6];
    const float* attn_w   = (const float*)d_in[7];
    float* out = (float*)d_out;

    char* w = (char*)d_ws;
    float* params = (float*)w; w += 256;
    float* part0  = (float*)w; w += NCELL * PSTRIDE * sizeof(float);
    float* part1  = (float*)w; w += NCELL * PSTRIDE * sizeof(float);
    float* s      = (float*)w; w += N_NODES * sizeof(float);
    float* s2     = (float*)w; w += N_NODES * sizeof(float);
    int*   cnt2   = (int*)w;   w += N_NODES * sizeof(int);
    int*   rcnt   = (int*)w;   w += N_NODES * CPAD * sizeof(int);
    int*   mlist  = (int*)w;   w += N_NODES * BCAP * sizeof(int);
    int*   bucket = (int*)w;

    k_init<<<(N_NODES * CPAD) / 256, 256, 0, stream>>>(attn_w, edge_emb, params,
                                                       rcnt, part0, part1);
    k_build<<<BUCKET_BLOCKS + MLP_BLOCKS, 256, 0, stream>>>(edges, rcnt, bucket,
                                                            X, W1, b1, W2, b2, s, part0);
    k_gather1<<<N_NODES / 4, 256, 0, stream>>>(rcnt, bucket, s, params, part0,
                                               s2, mlist, cnt2, part1);
    k_gather2<<<N_NODES / 4, 256, 0, stream>>>(cnt2, mlist, s2, params, part1, out);
}